// Round 9
// baseline (84.336 us; speedup 1.0000x reference)
//
#include <hip/hip_runtime.h>
#include <math.h>

#define LOG2E 1.4426950408889634f
#define LN2   0.6931471805599453f

typedef float v2f __attribute__((ext_vector_type(2)));

// Kernel A: coefficient precompute into SoA arrays (cf has 6*M floats):
//   cf[0*M+j] = -A_j*LOG2E   cf[1*M+j] = -B_j*LOG2E   cf[2*M+j] = -C_j*LOG2E
//   cf[3*M+j] = -D_j*LOG2E   cf[4*M+j] = -E_j*LOG2E   cf[5*M+j] =  K_j
// so that base-2 exponent e2 = K + A*xx + B*xy + C*yy + D*sx + E*sy.
__global__ __launch_bounds__(1024) void gm_params(
    const float* __restrict__ mu,         // (M,2)
    const float* __restrict__ sigma_log,  // (M,2)
    const float* __restrict__ theta,      // (M,)
    const float* __restrict__ w,          // (M,1)
    float* __restrict__ cf,               // (6*M,)
    float* __restrict__ out,
    int M)
{
    const int j = threadIdx.x;
    const int lane = j & 63;
    const int wid  = j >> 6;

    const float wj = w[j];

    // logsumexp over w (w ~ N(0,1): raw exp is safe)
    float e = __expf(wj);
    #pragma unroll
    for (int off = 32; off > 0; off >>= 1)
        e += __shfl_down(e, off, 64);

    __shared__ float ws[16];
    if (lane == 0) ws[wid] = e;
    __syncthreads();

    float tot = 0.0f;
    #pragma unroll
    for (int k = 0; k < 16; ++k) tot += ws[k];
    const float lse = __logf(tot);

    const float sl0 = sigma_log[2 * j + 0];
    const float sl1 = sigma_log[2 * j + 1];
    const float a = __expf(-2.0f * sl0);
    const float b = __expf(-2.0f * sl1);
    const float th = theta[j];
    const float c = __cosf(th);
    const float s = __sinf(th);

    const float g11 = a * c * c + b * s * s;
    const float g12 = (a - b) * c * s;
    const float g22 = a * s * s + b * c * c;

    const float mx = mu[2 * j + 0];
    const float my = mu[2 * j + 1];

    const float wlog = wj - lse - (sl0 + sl1);

    const float A = g11;
    const float B = 2.0f * g12;
    const float C = g22;
    const float D = -(2.0f * g11 * mx + 2.0f * g12 * my);
    const float E = -(2.0f * g12 * mx + 2.0f * g22 * my);
    const float F = g11 * mx * mx + 2.0f * g12 * mx * my + g22 * my * my;
    const float K = (wlog - F) * LOG2E;

    cf[0 * M + j] = -A * LOG2E;
    cf[1 * M + j] = -B * LOG2E;
    cf[2 * M + j] = -C * LOG2E;
    cf[3 * M + j] = -D * LOG2E;
    cf[4 * M + j] = -E * LOG2E;
    cf[5 * M + j] = K;

    if (j == 0) out[0] = 0.0f;
}

// Kernel B: register-resident components. Each lane owns 16 components
// (8 packed pairs, 96 VGPRs of coefficients loaded once, coalesced). The
// wave iterates over 16 samples; features are wave-uniform; the per-sample
// sum over all M components = lane partial + 6-step shfl_xor butterfly.
// Inner loop has zero memory operations.
__global__ __launch_bounds__(256) void gm_main(
    const float* __restrict__ sample,   // (N,2)
    const float* __restrict__ cf,       // (6*M,) SoA coefficients
    float* __restrict__ out,
    int M)
{
    const int lane = threadIdx.x & 63;
    int wid = __builtin_amdgcn_readfirstlane((int)(threadIdx.x >> 6)); // 0..3
    wid &= 3;
    const int wave = blockIdx.x * 4 + wid;   // 0..4095
    const int s0 = wave * 16;                // 16 samples per wave

    // Load this lane's 8 coefficient pairs (pair p = q*64 + lane).
    v2f cA[8], cB[8], cC[8], cD[8], cE[8], cK[8];
    {
        const v2f* A2 = (const v2f*)(cf + 0 * M);
        const v2f* B2 = (const v2f*)(cf + 1 * M);
        const v2f* C2 = (const v2f*)(cf + 2 * M);
        const v2f* D2 = (const v2f*)(cf + 3 * M);
        const v2f* E2 = (const v2f*)(cf + 4 * M);
        const v2f* K2 = (const v2f*)(cf + 5 * M);
        #pragma unroll
        for (int q = 0; q < 8; ++q) {
            const int p = q * 64 + lane;
            cA[q] = A2[p]; cB[q] = B2[p]; cC[q] = C2[p];
            cD[q] = D2[p]; cE[q] = E2[p]; cK[q] = K2[p];
        }
    }

    const float2* sam = (const float2*)sample;
    float nll = 0.0f;

    for (int it = 0; it < 16; ++it) {
        const float2 sv = sam[s0 + it];      // wave-uniform -> s_load
        const float sx = sv.x, sy = sv.y;
        const v2f xx = (v2f)(sx * sx);
        const v2f xy = (v2f)(sx * sy);
        const v2f yy = (v2f)(sy * sy);
        const v2f vx = (v2f)(sx);
        const v2f vy = (v2f)(sy);

        v2f a0 = (v2f)(0.0f), a1 = (v2f)(0.0f);
        #pragma unroll
        for (int q = 0; q < 8; ++q) {
            v2f e = cK[q];
            e = __builtin_elementwise_fma(cA[q], xx, e);
            e = __builtin_elementwise_fma(cB[q], xy, e);
            e = __builtin_elementwise_fma(cC[q], yy, e);
            e = __builtin_elementwise_fma(cD[q], vx, e);
            e = __builtin_elementwise_fma(cE[q], vy, e);
            v2f ex;
            ex.x = __builtin_amdgcn_exp2f(e.x);
            ex.y = __builtin_amdgcn_exp2f(e.y);
            if (q & 1) a1 += ex; else a0 += ex;
        }
        const v2f at = a0 + a1;
        float t = at.x + at.y;               // lane partial (16 comps)

        // butterfly: every lane ends with the full 1024-comp sum
        #pragma unroll
        for (int off = 32; off > 0; off >>= 1)
            t += __shfl_xor(t, off, 64);

        nll -= LN2 * __builtin_amdgcn_logf(t);
    }

    // block combine: 4 waves -> 1 atomic
    __shared__ float psum[4];
    if (lane == 0) psum[wid] = nll;
    __syncthreads();
    if (threadIdx.x == 0) {
        atomicAdd(out, (psum[0] + psum[1]) + (psum[2] + psum[3]));
    }
}

extern "C" void kernel_launch(void* const* d_in, const int* in_sizes, int n_in,
                              void* d_out, int out_size, void* d_ws, size_t ws_size,
                              hipStream_t stream) {
    const float* sample    = (const float*)d_in[0];
    const float* mu        = (const float*)d_in[1];
    const float* sigma_log = (const float*)d_in[2];
    const float* theta     = (const float*)d_in[3];
    const float* w         = (const float*)d_in[4];
    float* out = (float*)d_out;
    float* cf  = (float*)d_ws;

    const int M = in_sizes[3];      // 1024
    const int N = in_sizes[0] / 2;  // 65536

    gm_params<<<1, M, 0, stream>>>(mu, sigma_log, theta, w, cf, out, M);

    // 4096 waves: 16 samples/wave, 4 waves/block -> 1024 blocks
    const int grid = N / 64;
    gm_main<<<grid, 256, 0, stream>>>(sample, cf, out, M);
}